// Round 1
// baseline (213.793 us; speedup 1.0000x reference)
//
#include <hip/hip_runtime.h>
#include <hip/hip_bf16.h>

// ---------------------------------------------------------------------------
// SingleLayerMoE: T=1024 tokens, H=1024, E=8 experts, I=1024, top-2 routing.
// R5: double-buffered LDS, ONE barrier per 64-K phase (was 2): store(buf^1) +
//     global prefetch + MFMA(buf) share an inter-barrier region so the matrix
//     pipe and staging VALU overlap. Buffer index is compile-time (named
//     As0/As1, 2x-unrolled loop) so alias analysis can interleave ds ops.
//     4 launches: zero, router, gateup, down.
// ---------------------------------------------------------------------------

typedef unsigned short u16;
typedef __attribute__((ext_vector_type(8))) __bf16 bf16x8;
typedef __attribute__((ext_vector_type(4))) float f32x4;

#define T_TOK 1024
#define H_DIM 1024
#define E_NUM 8
#define I_DIM 1024
#define ALPHA 1.702f
#define LIMIT 7.0f
#define LSTR 72   // u16 row stride (36 dw): b128 frag reads ~2-way, b32 writes 2-way = free

__device__ __forceinline__ u16 f2bf(float f) {
    unsigned u = __builtin_bit_cast(unsigned, f);
    u = (u + 0x7FFFu + ((u >> 16) & 1u)) >> 16;
    return (u16)u;
}

// pack two fp32 -> bf16x2 (RNE); HW v_cvt_pk_bf16_f32 when available
__device__ __forceinline__ unsigned pk2(float lo, float hi) {
#if defined(__has_builtin) && __has_builtin(__builtin_amdgcn_cvt_pk_bf16_f32)
    typedef __attribute__((ext_vector_type(2))) __bf16 bf16x2_t;
    bf16x2_t v = __builtin_amdgcn_cvt_pk_bf16_f32(lo, hi);
    return __builtin_bit_cast(unsigned, v);
#else
    return (unsigned)f2bf(lo) | ((unsigned)f2bf(hi) << 16);
#endif
}

__device__ __forceinline__ f32x4 mfma16(bf16x8 a, bf16x8 b, f32x4 c) {
    return __builtin_amdgcn_mfma_f32_16x16x32_bf16(a, b, c, 0, 0, 0);
}

// expert count + prefix base from counts[8] (no array -> no scratch)
__device__ __forceinline__ void expert_range(const int* counts, int e,
                                             int& cnt, int& abase) {
    int a = 0, c = 0;
#pragma unroll
    for (int i = 0; i < E_NUM; ++i) {
        int v = counts[i];
        if (i < e) a += v;
        if (i == e) c = v;
    }
    cnt = c; abase = a;
}

// --------------------------- K0: zero counters ------------------------------
__global__ void k_zero(int* counts) {
    if (threadIdx.x < E_NUM) counts[threadIdx.x] = 0;
}

// ------------- K1: router + dispatch + x->bf16 + weighted-bias out ----------
__global__ __launch_bounds__(256) void k_router(
    const float* __restrict__ x, const float* __restrict__ rw,
    const float* __restrict__ rb, const float* __restrict__ db,
    int* __restrict__ counts, int* __restrict__ tok_list,
    float* __restrict__ w_list, u16* __restrict__ xb,
    float* __restrict__ out)
{
    const int t = blockIdx.x;
    const int tid = threadIdx.x;
    const float4 xv = *(const float4*)(x + (size_t)t * H_DIM + tid * 4);

    // bf16 copy of hidden state (A operand for gate_up GEMM)
    *(uint2*)(xb + (size_t)t * H_DIM + tid * 4) =
        make_uint2(pk2(xv.x, xv.y), pk2(xv.z, xv.w));

    float p[E_NUM];
#pragma unroll
    for (int e = 0; e < E_NUM; ++e) {
        const float4 wv = *(const float4*)(rw + e * H_DIM + tid * 4);
        p[e] = xv.x * wv.x + xv.y * wv.y + xv.z * wv.z + xv.w * wv.w;
    }
#pragma unroll
    for (int off = 32; off; off >>= 1) {
#pragma unroll
        for (int e = 0; e < E_NUM; ++e) p[e] += __shfl_down(p[e], off, 64);
    }
    __shared__ float red[4][E_NUM];
    __shared__ int se[2];
    __shared__ float sw[2];
    const int lane = tid & 63, wvid = tid >> 6;
    if (lane == 0) {
#pragma unroll
        for (int e = 0; e < E_NUM; ++e) red[wvid][e] = p[e];
    }
    __syncthreads();
    if (tid == 0) {
        float lg[E_NUM];
#pragma unroll
        for (int e = 0; e < E_NUM; ++e)
            lg[e] = red[0][e] + red[1][e] + red[2][e] + red[3][e] + rb[e];
        float m1 = -1e30f, m2 = -1e30f; int i1 = 0, i2 = 0;
#pragma unroll
        for (int e = 0; e < E_NUM; ++e) {
            float l = lg[e];
            if (l > m1) { m2 = m1; i2 = i1; m1 = l; i1 = e; }
            else if (l > m2) { m2 = l; i2 = e; }
        }
        float s = 0.f;
#pragma unroll
        for (int e = 0; e < E_NUM; ++e) s += __expf(lg[e] - m1);
        const float w0 = 1.0f / s;
        const float w1 = __expf(m2 - m1) / s;
        int slot0 = atomicAdd(&counts[i1], 1);
        tok_list[i1 * T_TOK + slot0] = t;
        w_list[i1 * T_TOK + slot0] = w0;
        int slot1 = atomicAdd(&counts[i2], 1);
        tok_list[i2 * T_TOK + slot1] = t;
        w_list[i2 * T_TOK + slot1] = w1;
        se[0] = i1; se[1] = i2; sw[0] = w0; sw[1] = w1;
    }
    __syncthreads();
    // out = w0*bias[e0] + w1*bias[e1]; down-GEMM atomically accumulates on top
    const int e0 = se[0], e1 = se[1];
    const float w0 = sw[0], w1 = sw[1];
    const int c = tid * 4;
    float4 d0 = *(const float4*)(db + e0 * H_DIM + c);
    float4 d1 = *(const float4*)(db + e1 * H_DIM + c);
    float4 o;
    o.x = w0 * d0.x + w1 * d1.x;
    o.y = w0 * d0.y + w1 * d1.y;
    o.z = w0 * d0.z + w1 * d1.z;
    o.w = w0 * d0.w + w1 * d1.w;
    *(float4*)(out + (size_t)t * H_DIM + c) = o;
}

// --------------------------- K2: gate_up GEMM + GLU -------------------------
// tile 64 rows x (32 gate + 32 up), BK=64, double-buffered LDS, 1 barrier per
// 64-K phase; grid (32 strips, 16 m, 8 e).
__global__ __launch_bounds__(256, 4) void k_gateup(
    const float* __restrict__ gup, const float* __restrict__ gub,
    const int* __restrict__ counts, const int* __restrict__ tok_list,
    const u16* __restrict__ xb, u16* __restrict__ act)
{
    const int e = blockIdx.z;
    int cnt, abase;
    expert_range(counts, e, cnt, abase);
    const int m0 = blockIdx.y * 64;
    if (m0 >= cnt) return;
    const int n0 = blockIdx.x * 32;
    const int tid = threadIdx.x;

    __shared__ __align__(16) u16 As0[64 * LSTR];   // 9.2 KB each
    __shared__ __align__(16) u16 Bs0[64 * LSTR];   // rows 0..31 gate, 32..63 up
    __shared__ __align__(16) u16 As1[64 * LSTR];
    __shared__ __align__(16) u16 Bs1[64 * LSTR];
    unsigned* B32_0 = (unsigned*)Bs0;
    unsigned* B32_1 = (unsigned*)Bs1;

    // A staging: row = tid>>2, k-quarter = (tid&3)*16
    const int arow_i = tid >> 2, akq = (tid & 3) * 16;
    const int aslot = m0 + arow_i;
    const int atok = (aslot < cnt) ? tok_list[e * T_TOK + aslot] : 0;
    const u16* asrc = xb + (size_t)atok * H_DIM + akq;
    u16* adst0 = &As0[arow_i * LSTR + akq];
    u16* adst1 = &As1[arow_i * LSTR + akq];

    // B staging: kp = tid>>3 (k-pair 2kp,2kp+1), q = tid&7 (col quad)
    const int kp = tid >> 3, q = tid & 7;
    const float* bgate = gup + ((size_t)e << 21) + n0 + q * 4;

    const int lane = tid & 63, wv = tid >> 6;
    const int fm = lane & 15, kg = lane >> 4;

    f32x4 accg[2], accu[2];
#pragma unroll
    for (int nt = 0; nt < 2; ++nt) {
        accg[nt] = (f32x4){0.f, 0.f, 0.f, 0.f};
        accu[nt] = (f32x4){0.f, 0.f, 0.f, 0.f};
    }

#define GU_LOAD(A0, A1, G0, G1, U0, U1, KB)                                    \
    {                                                                          \
        const u16* ap_ = asrc + (KB);                                          \
        A0 = *(const uint4*)(ap_);                                             \
        A1 = *(const uint4*)(ap_ + 8);                                         \
        const float* gp_ = bgate + (size_t)((KB) + 2 * kp) * 2048;             \
        G0 = *(const float4*)(gp_);                                            \
        G1 = *(const float4*)(gp_ + 2048);                                     \
        U0 = *(const float4*)(gp_ + 1024);                                     \
        U1 = *(const float4*)(gp_ + 3072);                                     \
    }
#define GU_STORE(AD, B32, A0, A1, G0, G1, U0, U1)                              \
    {                                                                          \
        *(uint4*)(AD)       = A0;                                              \
        *(uint4*)((AD) + 8) = A1;                                              \
        const float* g0_ = (const float*)&G0; const float* g1_ = (const float*)&G1; \
        const float* u0_ = (const float*)&U0; const float* u1_ = (const float*)&U1; \
        _Pragma("unroll")                                                      \
        for (int j = 0; j < 4; ++j) {                                          \
            B32[(q * 4 + j) * 36 + kp]        = pk2(g0_[j], g1_[j]);           \
            B32[(32 + q * 4 + j) * 36 + kp]   = pk2(u0_[j], u1_[j]);           \
        }                                                                      \
    }
#define GU_MFMA(AS, BS)                                                        \
    {                                                                          \
        _Pragma("unroll")                                                      \
        for (int sub = 0; sub < 2; ++sub) {                                    \
            bf16x8 af = *(const bf16x8*)&AS[(wv * 16 + fm) * LSTR + sub * 32 + kg * 8]; \
            _Pragma("unroll")                                                  \
            for (int nt = 0; nt < 2; ++nt) {                                   \
                bf16x8 bg = *(const bf16x8*)&BS[(nt * 16 + fm) * LSTR + sub * 32 + kg * 8]; \
                bf16x8 bu = *(const bf16x8*)&BS[(32 + nt * 16 + fm) * LSTR + sub * 32 + kg * 8]; \
                accg[nt] = mfma16(af, bg, accg[nt]);                           \
                accu[nt] = mfma16(af, bu, accu[nt]);                           \
            }                                                                  \
        }                                                                      \
    }

    uint4 a0s0, a1s0, a0s1, a1s1;
    float4 g0s0, g1s0, u0s0, u1s0, g0s1, g1s1, u0s1, u1s1;
    // prologue: fill buf0 (k=0), prefetch k=64 (set1) and k=128 (set0)
    GU_LOAD(a0s0, a1s0, g0s0, g1s0, u0s0, u1s0, 0);
    GU_LOAD(a0s1, a1s1, g0s1, g1s1, u0s1, u1s1, 64);
    GU_STORE(adst0, B32_0, a0s0, a1s0, g0s0, g1s0, u0s0, u1s0);
    GU_LOAD(a0s0, a1s0, g0s0, g1s0, u0s0, u1s0, 128);
    __syncthreads();

    for (int kb = 0; kb < H_DIM; kb += 128) {
        // phase A: compute buf0 (k=kb), fill buf1 (k=kb+64), load k=kb+192
        GU_STORE(adst1, B32_1, a0s1, a1s1, g0s1, g1s1, u0s1, u1s1);
        if (kb + 192 < H_DIM)
            GU_LOAD(a0s1, a1s1, g0s1, g1s1, u0s1, u1s1, kb + 192);
        GU_MFMA(As0, Bs0);
        __syncthreads();
        // phase B: compute buf1 (k=kb+64), fill buf0 (k=kb+128), load kb+256
        if (kb + 128 < H_DIM) {
            GU_STORE(adst0, B32_0, a0s0, a1s0, g0s0, g1s0, u0s0, u1s0);
            if (kb + 256 < H_DIM)
                GU_LOAD(a0s0, a1s0, g0s0, g1s0, u0s0, u1s0, kb + 256);
        }
        GU_MFMA(As1, Bs1);
        __syncthreads();
    }
#undef GU_LOAD
#undef GU_STORE
#undef GU_MFMA

    // epilogue: bias + clamped GLU -> compact bf16 act rows
#pragma unroll
    for (int r = 0; r < 4; ++r) {
        int rowb = wv * 16 + kg * 4 + r;       // C/D: row=(lane>>4)*4+reg
        int slot = m0 + rowb;
        if (slot >= cnt) continue;
        size_t arow_o = (size_t)(abase + slot) * I_DIM;
#pragma unroll
        for (int nt = 0; nt < 2; ++nt) {
            int cn = n0 + nt * 16 + fm;        // C/D: col=lane&15
            float g = accg[nt][r] + gub[e * 2048 + cn];
            float u = accu[nt][r] + gub[e * 2048 + 1024 + cn];
            g = fminf(g, LIMIT);
            u = fminf(fmaxf(u, -LIMIT), LIMIT);
            float glu = g / (1.f + __expf(-ALPHA * g));
            act[arow_o + cn] = f2bf((u + 1.f) * glu);
        }
    }
}

// ---------------- K3: down GEMM * w, atomic combine into out ----------------
// tile 64 rows x 64 cols, K-split 2 (512 each), BK=64, double-buffered LDS,
// 1 barrier per 64-K phase; grid (16 strips, 16 m, 8 e * 2 ks).
__global__ __launch_bounds__(256, 4) void k_down(
    const float* __restrict__ dp,
    const int* __restrict__ counts, const int* __restrict__ tok_list,
    const float* __restrict__ w_list,
    const u16* __restrict__ act, float* __restrict__ out)
{
    const int e = blockIdx.z & 7, ks = blockIdx.z >> 3;
    int cnt, abase;
    expert_range(counts, e, cnt, abase);
    const int m0 = blockIdx.y * 64;
    if (m0 >= cnt) return;
    const int n0 = blockIdx.x * 64;
    const int tid = threadIdx.x;

    __shared__ __align__(16) u16 As0[64 * LSTR];
    __shared__ __align__(16) u16 Bs0[64 * LSTR];
    __shared__ __align__(16) u16 As1[64 * LSTR];
    __shared__ __align__(16) u16 Bs1[64 * LSTR];
    unsigned* B32_0 = (unsigned*)Bs0;
    unsigned* B32_1 = (unsigned*)Bs1;

    const int arow_i = tid >> 2, akq = (tid & 3) * 16;
    // rows past cnt read slack rows (finite), masked at store
    const u16* asrc = act + (size_t)(abase + m0 + arow_i) * I_DIM + ks * 512 + akq;
    u16* adst0 = &As0[arow_i * LSTR + akq];
    u16* adst1 = &As1[arow_i * LSTR + akq];

    const int kp = tid >> 3, q = tid & 7;     // cols 4q..4q+3 and 32+4q..
    const float* bsrc = dp + ((size_t)e << 20) + (size_t)(ks * 512) * 1024 + n0 + q * 4;

    const int lane = tid & 63, wv = tid >> 6;
    const int fm = lane & 15, kg = lane >> 4;

    f32x4 acc[4];
#pragma unroll
    for (int nt = 0; nt < 4; ++nt) acc[nt] = (f32x4){0.f, 0.f, 0.f, 0.f};

#define DN_LOAD(A0, A1, B00, B01, B10, B11, KB)                                \
    {                                                                          \
        const u16* ap_ = asrc + (KB);                                          \
        A0 = *(const uint4*)(ap_);                                             \
        A1 = *(const uint4*)(ap_ + 8);                                         \
        const float* bp_ = bsrc + (size_t)((KB) + 2 * kp) * 1024;              \
        B00 = *(const float4*)(bp_);                                           \
        B01 = *(const float4*)(bp_ + 1024);                                    \
        B10 = *(const float4*)(bp_ + 32);                                      \
        B11 = *(const float4*)(bp_ + 1056);                                    \
    }
#define DN_STORE(AD, B32, A0, A1, B00, B01, B10, B11)                          \
    {                                                                          \
        *(uint4*)(AD)       = A0;                                              \
        *(uint4*)((AD) + 8) = A1;                                              \
        const float* b00_ = (const float*)&B00; const float* b01_ = (const float*)&B01; \
        const float* b10_ = (const float*)&B10; const float* b11_ = (const float*)&B11; \
        _Pragma("unroll")                                                      \
        for (int j = 0; j < 4; ++j) {                                          \
            B32[(q * 4 + j) * 36 + kp]      = pk2(b00_[j], b01_[j]);           \
            B32[(32 + q * 4 + j) * 36 + kp] = pk2(b10_[j], b11_[j]);           \
        }                                                                      \
    }
#define DN_MFMA(AS, BS)                                                        \
    {                                                                          \
        _Pragma("unroll")                                                      \
        for (int sub = 0; sub < 2; ++sub) {                                    \
            bf16x8 af = *(const bf16x8*)&AS[(wv * 16 + fm) * LSTR + sub * 32 + kg * 8]; \
            _Pragma("unroll")                                                  \
            for (int nt = 0; nt < 4; ++nt) {                                   \
                bf16x8 b = *(const bf16x8*)&BS[(nt * 16 + fm) * LSTR + sub * 32 + kg * 8]; \
                acc[nt] = mfma16(af, b, acc[nt]);                              \
            }                                                                  \
        }                                                                      \
    }

    uint4 a0s0, a1s0, a0s1, a1s1;
    float4 b00s0, b01s0, b10s0, b11s0, b00s1, b01s1, b10s1, b11s1;
    // prologue: fill buf0 (k=0), prefetch k=64 (set1) and k=128 (set0)
    DN_LOAD(a0s0, a1s0, b00s0, b01s0, b10s0, b11s0, 0);
    DN_LOAD(a0s1, a1s1, b00s1, b01s1, b10s1, b11s1, 64);
    DN_STORE(adst0, B32_0, a0s0, a1s0, b00s0, b01s0, b10s0, b11s0);
    DN_LOAD(a0s0, a1s0, b00s0, b01s0, b10s0, b11s0, 128);
    __syncthreads();

    for (int kb = 0; kb < 512; kb += 128) {
        // phase A: compute buf0 (k=kb), fill buf1 (k=kb+64), load k=kb+192
        DN_STORE(adst1, B32_1, a0s1, a1s1, b00s1, b01s1, b10s1, b11s1);
        if (kb + 192 < 512)
            DN_LOAD(a0s1, a1s1, b00s1, b01s1, b10s1, b11s1, kb + 192);
        DN_MFMA(As0, Bs0);
        __syncthreads();
        // phase B: compute buf1 (k=kb+64), fill buf0 (k=kb+128), load kb+256
        if (kb + 128 < 512) {
            DN_STORE(adst0, B32_0, a0s0, a1s0, b00s0, b01s0, b10s0, b11s0);
            if (kb + 256 < 512)
                DN_LOAD(a0s0, a1s0, b00s0, b01s0, b10s0, b11s0, kb + 256);
        }
        DN_MFMA(As1, Bs1);
        __syncthreads();
    }
#undef DN_LOAD
#undef DN_STORE
#undef DN_MFMA

#pragma unroll
    for (int r = 0; r < 4; ++r) {
        int rowb = wv * 16 + kg * 4 + r;
        int slot = m0 + rowb;
        if (slot >= cnt) continue;
        float wgt = w_list[e * T_TOK + slot];
        int tok = tok_list[e * T_TOK + slot];
        float* orow = out + (size_t)tok * H_DIM + n0;
#pragma unroll
        for (int nt = 0; nt < 4; ++nt)
            atomicAdd(orow + nt * 16 + fm, acc[nt][r] * wgt);
    }
}

// ---------------------------------------------------------------------------
extern "C" void kernel_launch(void* const* d_in, const int* in_sizes, int n_in,
                              void* d_out, int out_size, void* d_ws, size_t ws_size,
                              hipStream_t stream) {
    const float* x   = (const float*)d_in[0]; // [1,1024,1024]
    const float* rw  = (const float*)d_in[1]; // [8,1024]
    const float* rb  = (const float*)d_in[2]; // [8]
    const float* gup = (const float*)d_in[3]; // [8,1024,2048]
    const float* gub = (const float*)d_in[4]; // [8,2048]
    const float* dp  = (const float*)d_in[5]; // [8,1024,1024]
    const float* db  = (const float*)d_in[6]; // [8,1024]
    float* out = (float*)d_out;

    char* ws = (char*)d_ws;
    int*   counts   = (int*)(ws);                    // 8 ints
    int*   tok_list = (int*)(ws + 64);               // 8*1024 ints (32 KB)
    float* w_list   = (float*)(ws + 64 + 32768);     // 8*1024 f32  (32 KB)
    u16*   xb       = (u16*)(ws + 65600);            // 1024*1024 bf16 (2 MB)
    u16*   act      = (u16*)(ws + 65600 + 2097152);  // 2112*1024 bf16 (4.125 MB + slack)

    k_zero<<<1, 64, 0, stream>>>(counts);
    k_router<<<T_TOK, 256, 0, stream>>>(x, rw, rb, db, counts, tok_list, w_list,
                                        xb, out);
    k_gateup<<<dim3(32, 16, 8), 256, 0, stream>>>(gup, gub, counts, tok_list,
                                                  xb, act);
    k_down<<<dim3(16, 16, 16), 256, 0, stream>>>(dp, counts, tok_list, w_list,
                                                 act, out);
}